// Round 12
// baseline (3367.191 us; speedup 1.0000x reference)
//
#include <hip/hip_runtime.h>
#include <math.h>

#define NB 4
#define L0 8192
#define CR 32
#define CD 32
#define CS 512
#define CE 256
#define NV 256
#define OUT_T 5632
#define XSTRIDE 8192
#define NL 50
#define KCAT 1600   // 50 * 32

typedef __attribute__((ext_vector_type(8))) short  short8;
typedef __attribute__((ext_vector_type(4))) float  f32x4;
typedef __attribute__((ext_vector_type(4))) float  f4;
typedef __attribute__((ext_vector_type(4))) unsigned short us4;

static __device__ __forceinline__ unsigned short f2bf(float f) {
    unsigned int u = __builtin_bit_cast(unsigned int, f);
    u = (u + 0x7FFFu + ((u >> 16) & 1u)) >> 16;
    return (unsigned short)u;
}

// ---------------- Kernel P: weight f32 -> bf16 prep ----------------
__global__ __launch_bounds__(256) void k_prep(const float* __restrict__ sw,
                                              const float* __restrict__ w1,
                                              const float* __restrict__ w2,
                                              unsigned short* __restrict__ wsb,
                                              unsigned short* __restrict__ w1b,
                                              unsigned short* __restrict__ w2b)
{
    int idx = blockIdx.x * 256 + threadIdx.x;
    if (idx < NL * CS * CD) {
        int l = idx >> 14;
        int co = (idx >> 5) & 511;
        int c = idx & 31;
        wsb[co * KCAT + l * 32 + c] = f2bf(sw[idx]);
    } else if (idx < NL * CS * CD + CE * CS) {
        int e = idx - NL * CS * CD;
        w1b[e] = f2bf(w1[e]);
    } else {
        int e = idx - NL * CS * CD - CE * CS;
        w2b[e] = f2bf(w2[e]);
    }
}

// ---------------- Kernel A: embedding + causal pre-conv, XCD-sliced ----------------
// XCD k owns (batch = k>>1, half = k&1): writes land in that XCD's L2 slice.
__global__ __launch_bounds__(256) void k_pre(const int* __restrict__ tokens,
                                             const float* __restrict__ emb,
                                             const float* __restrict__ pw,
                                             float* __restrict__ x)
{
    int bid = blockIdx.x;
    int xcd = bid & 7;
    int b = xcd >> 1;
    int half = xcd & 1;
    int r = bid >> 3;            // [0, 512)
    int ch = r >> 4;
    int seg = r & 15;
    int t = half * (L0 / 2) + seg * 256 + threadIdx.x;

    const int* tb = tokens + b * L0;
    const float* e1 = emb + tb[t] * CR;
    const float* w = pw + ch * CR * 2;
    float acc = 0.f;
    if (t > 0) {
        const float* e0 = emb + tb[t - 1] * CR;
#pragma unroll
        for (int i = 0; i < CR; ++i)
            acc += w[i * 2] * e0[i] + w[i * 2 + 1] * e1[i];
    } else {
#pragma unroll
        for (int i = 0; i < CR; ++i)
            acc += w[i * 2 + 1] * e1[i];
    }
    x[(b * CR + ch) * XSTRIDE + t] = acc;
}

// ---------------- per-layer tile body (round-3 numerics, unchanged) ----------------
struct LayerSmem {
    float As[32][68];
    float Bs[32][68];
    float Zs[32][68];
    unsigned short ZsT[64][32];
    float wfT[64][33];
    float wgT[64][33];
    float rwT[32][33];
};

static __device__ __forceinline__ void layer_tile(
    LayerSmem& sm, int tid, int b, int t0,
    const float* __restrict__ x_in, float* __restrict__ x_out,
    unsigned short* __restrict__ Zt,
    const float* __restrict__ fw, const float* __restrict__ gw,
    const float* __restrict__ rw,
    int T_out, int d, int P, int skipOff, int kOff)
{
    const float* xb = x_in + b * CR * XSTRIDE;
    for (int e = tid; e < 2048; e += 256) {
        int c = e >> 6, i2 = e & 63;
        sm.wfT[i2][c] = fw[e];
        sm.wgT[i2][c] = gw[e];
    }
    for (int e = tid; e < 1024; e += 256) {
        int c = e >> 5, i = e & 31;
        sm.rwT[i][c] = rw[e];
    }
    {
        int ch = tid >> 3;
        int j0 = (tid & 7) * 8;
        const float* row = xb + ch * XSTRIDE;
#pragma unroll
        for (int k = 0; k < 8; ++k) {
            int t = t0 + j0 + k;
            float a = 0.f, bb = 0.f;
            if (t < T_out) {
                if (t >= P) a = row[t - P];
                bb = row[t + d - P];
            }
            sm.As[ch][j0 + k] = a;
            sm.Bs[ch][j0 + k] = bb;
        }
    }
    __syncthreads();
    {
        int c = tid & 31;
        int j0 = (tid >> 5) * 8;
        float af[8] = {0, 0, 0, 0, 0, 0, 0, 0};
        float ag[8] = {0, 0, 0, 0, 0, 0, 0, 0};
#pragma unroll
        for (int i = 0; i < 32; ++i) {
            float av[8], bv[8];
            *(f4*)&av[0] = *(const f4*)&sm.As[i][j0];
            *(f4*)&av[4] = *(const f4*)&sm.As[i][j0 + 4];
            *(f4*)&bv[0] = *(const f4*)&sm.Bs[i][j0];
            *(f4*)&bv[4] = *(const f4*)&sm.Bs[i][j0 + 4];
            float f0 = sm.wfT[2 * i][c], f1 = sm.wfT[2 * i + 1][c];
            float g0 = sm.wgT[2 * i][c], g1 = sm.wgT[2 * i + 1][c];
#pragma unroll
            for (int k = 0; k < 8; ++k) {
                af[k] += f0 * av[k] + f1 * bv[k];
                ag[k] += g0 * av[k] + g1 * bv[k];
            }
        }
#pragma unroll
        for (int k = 0; k < 8; ++k) {
            float e2a = __expf(2.f * af[k]);
            float th = 1.f - __fdividef(2.f, e2a + 1.f);
            float sg = __fdividef(1.f, 1.f + __expf(-ag[k]));
            float z = th * sg;
            sm.Zs[c][j0 + k] = z;
            sm.ZsT[j0 + k][c] = f2bf(z);
        }
    }
    __syncthreads();
    {
        int ch = tid >> 3;
        int j0 = (tid & 7) * 8;
        float accv[8];
        *(f4*)&accv[0] = *(const f4*)&sm.Bs[ch][j0];
        *(f4*)&accv[4] = *(const f4*)&sm.Bs[ch][j0 + 4];
#pragma unroll
        for (int i = 0; i < 32; ++i) {
            float w = sm.rwT[i][ch];
            float zv[8];
            *(f4*)&zv[0] = *(const f4*)&sm.Zs[i][j0];
            *(f4*)&zv[4] = *(const f4*)&sm.Zs[i][j0 + 4];
#pragma unroll
            for (int k = 0; k < 8; ++k)
                accv[k] += w * zv[k];
        }
        float* orow = x_out + (b * CR + ch) * XSTRIDE;
#pragma unroll
        for (int k = 0; k < 8; ++k) {
            int t = t0 + j0 + k;
            if (t < T_out) orow[t] = accv[k];
        }
    }
    {
        int tl = tid >> 2;
        int cq = (tid & 3) * 8;
        int t = t0 + tl;
        if (t >= skipOff && t < T_out) {
            unsigned short* dst =
                Zt + ((size_t)b * OUT_T + (t - skipOff)) * KCAT + kOff + cq;
            *(short8*)dst = *(const short8*)&sm.ZsT[tl][cq];
        }
    }
}

// ---------------- Kernel B: one layer, XCD-sliced block mapping ----------------
// bid&7 -> XCD -> (batch = xcd>>1, time-half = xcd&1); same slice every layer,
// so x tiles written by layer l are read by layer l+1 on the same XCD.
__global__ __launch_bounds__(256, 3) void k_layer(
    const float* __restrict__ x_in, float* __restrict__ x_out,
    unsigned short* __restrict__ Zt,
    const float* __restrict__ fw, const float* __restrict__ gw,
    const float* __restrict__ rw,
    int T_out, int d, int P, int skipOff, int kOff, int tiles_half)
{
    int bid = blockIdx.x;
    int xcd = bid & 7;
    int b = xcd >> 1;
    int half = xcd & 1;
    int tile = half * tiles_half + (bid >> 3);
    if (tile >= ((T_out + 63) >> 6)) return;   // uniform per block
    __shared__ LayerSmem sm;
    layer_tile(sm, threadIdx.x, b, tile * 64,
               x_in, x_out, Zt, fw, gw, rw, T_out, d, P, skipOff, kOff);
}

// ---------------- MFMA GEMM: C[b] = A * B[b]^T(+bias)(+relu), 128x128 tile ----------------
template <int MODE>
__global__ __launch_bounds__(256) void k_gemm(
    const unsigned short* __restrict__ A,
    const unsigned short* __restrict__ B,
    const float* __restrict__ bias,
    void* __restrict__ Cout, int M, int K)
{
    __shared__ unsigned short Asm[128][72];
    __shared__ unsigned short Bsm[128][72];
    const int tid = threadIdx.x;
    const int n0 = blockIdx.x * 128;
    const int m0 = blockIdx.y * 128;
    const int b = blockIdx.z;
    const unsigned short* Bb = B + (size_t)b * OUT_T * K;
    const int lane = tid & 63;
    const int wm = tid >> 6;
    f32x4 acc[2][8];
#pragma unroll
    for (int fm = 0; fm < 2; ++fm)
#pragma unroll
        for (int fn = 0; fn < 8; ++fn)
            acc[fm][fn] = (f32x4){0.f, 0.f, 0.f, 0.f};

    for (int kb = 0; kb < K; kb += 64) {
        __syncthreads();
#pragma unroll
        for (int it = 0; it < 4; ++it) {
            int lin = tid + it * 256;
            int row = lin >> 3, c8 = (lin & 7) * 8;
            *(short8*)&Asm[row][c8] =
                *(const short8*)&A[(size_t)(m0 + row) * K + kb + c8];
        }
#pragma unroll
        for (int it = 0; it < 4; ++it) {
            int lin = tid + it * 256;
            int row = lin >> 3, c8 = (lin & 7) * 8;
            *(short8*)&Bsm[row][c8] =
                *(const short8*)&Bb[(size_t)(n0 + row) * K + kb + c8];
        }
        __syncthreads();
#pragma unroll
        for (int kk = 0; kk < 2; ++kk) {
            short8 a[2], bb[8];
#pragma unroll
            for (int fm = 0; fm < 2; ++fm)
                a[fm] = *(const short8*)&Asm[wm * 32 + fm * 16 + (lane & 15)]
                                           [kk * 32 + (lane >> 4) * 8];
#pragma unroll
            for (int fn = 0; fn < 8; ++fn)
                bb[fn] = *(const short8*)&Bsm[fn * 16 + (lane & 15)]
                                            [kk * 32 + (lane >> 4) * 8];
#pragma unroll
            for (int fm = 0; fm < 2; ++fm)
#pragma unroll
                for (int fn = 0; fn < 8; ++fn)
                    acc[fm][fn] = __builtin_amdgcn_mfma_f32_16x16x32_bf16(
                        a[fm], bb[fn], acc[fm][fn], 0, 0, 0);
        }
    }
#pragma unroll
    for (int fm = 0; fm < 2; ++fm) {
        int mb = m0 + wm * 32 + fm * 16 + (lane >> 4) * 4;
#pragma unroll
        for (int fn = 0; fn < 8; ++fn) {
            int n = n0 + fn * 16 + (lane & 15);
            float v[4];
#pragma unroll
            for (int r = 0; r < 4; ++r) {
                v[r] = acc[fm][fn][r];
                if (MODE >= 1) v[r] += bias[mb + r];
                if (MODE <= 1) v[r] = v[r] > 0.f ? v[r] : 0.f;
            }
            if (MODE == 2) {
                float* o = (float*)Cout;
#pragma unroll
                for (int r = 0; r < 4; ++r)
                    o[((size_t)b * NV + mb + r) * OUT_T + n] = v[r];
            } else {
                unsigned short* o = (unsigned short*)Cout;
                us4 pk;
#pragma unroll
                for (int r = 0; r < 4; ++r) pk[r] = f2bf(v[r]);
                *(us4*)&o[((size_t)b * OUT_T + n) * M + mb] = pk;
            }
        }
    }
}

extern "C" void kernel_launch(void* const* d_in, const int* in_sizes, int n_in,
                              void* d_out, int out_size, void* d_ws, size_t ws_size,
                              hipStream_t stream)
{
    const int*   tokens  = (const int*)d_in[0];
    const float* emb     = (const float*)d_in[1];
    const float* pre_w   = (const float*)d_in[2];
    const float* filt_w  = (const float*)d_in[3];
    const float* gate_w  = (const float*)d_in[4];
    const float* res_w   = (const float*)d_in[5];
    const float* skip_w  = (const float*)d_in[6];
    const float* post_w1 = (const float*)d_in[7];
    const float* post_b1 = (const float*)d_in[8];
    const float* post_w2 = (const float*)d_in[9];
    const float* post_b2 = (const float*)d_in[10];
    float* out = (float*)d_out;

    char* ws = (char*)d_ws;
    float* xA = (float*)ws;                 ws += (size_t)NB * CR * XSTRIDE * 4;
    float* xB = (float*)ws;                 ws += (size_t)NB * CR * XSTRIDE * 4;
    unsigned short* Zt    = (unsigned short*)ws; ws += (size_t)NB * OUT_T * KCAT * 2;
    unsigned short* skipT = (unsigned short*)ws; ws += (size_t)NB * OUT_T * CS * 2;
    unsigned short* h1T   = (unsigned short*)ws; ws += (size_t)NB * OUT_T * CE * 2;
    unsigned short* wsb   = (unsigned short*)ws; ws += (size_t)CS * KCAT * 2;
    unsigned short* w1b   = (unsigned short*)ws; ws += (size_t)CE * CS * 2;
    unsigned short* w2b   = (unsigned short*)ws; ws += (size_t)NV * CE * 2;

    k_prep<<<3968, 256, 0, stream>>>(skip_w, post_w1, post_w2, wsb, w1b, w2b);
    k_pre<<<(NB * CR * L0) / 256, 256, 0, stream>>>(tokens, emb, pre_w, xA);

    // static layer schedule (mirrors reference dilate() padding)
    int dArr[NL], pArr[NL], tArr[NL];
    {
        int T = L0, init = 1, li = 0;
        for (int blk = 0; blk < 5; ++blk) {
            int nw = 1;
            for (int j = 0; j < 10; ++j) {
                int d = nw, P = 0;
                if (d > init) {
                    int r = d / init;
                    int l = T / init;
                    int nl = ((l + r - 1) / r) * r;
                    P = (nl - l) * init;
                }
                int T_out = T + P - d;
                dArr[li] = d; pArr[li] = P; tArr[li] = T_out;
                T = T_out; init = d; nw <<= 1; ++li;
            }
        }
    }

    float* xin = xA;
    float* xout = xB;
    for (int li = 0; li < NL; ++li) {
        int T_out = tArr[li];
        int ntiles = (T_out + 63) / 64;
        int tiles_half = (ntiles + 1) / 2;
        k_layer<<<dim3(8 * tiles_half), 256, 0, stream>>>(
            xin, xout, Zt,
            filt_w + (size_t)li * CD * CR * 2,
            gate_w + (size_t)li * CD * CR * 2,
            res_w + (size_t)li * CR * CD,
            T_out, dArr[li], pArr[li], T_out - OUT_T, li * 32, tiles_half);
        float* tmp = xin; xin = xout; xout = tmp;
    }

    dim3 gs(OUT_T / 128, CS / 128, NB);
    k_gemm<0><<<gs, 256, 0, stream>>>(wsb, Zt, nullptr, skipT, CS, KCAT);
    dim3 g1(OUT_T / 128, CE / 128, NB);
    k_gemm<1><<<g1, 256, 0, stream>>>(w1b, skipT, post_b1, h1T, CE, CS);
    dim3 g2(OUT_T / 128, NV / 128, NB);
    k_gemm<2><<<g2, 256, 0, stream>>>(w2b, h1T, post_b2, out, NV, CE);
}

// Round 13
// 1401.658 us; speedup vs baseline: 2.4023x; 2.4023x over previous
//
#include <hip/hip_runtime.h>
#include <math.h>

#define NB 4
#define L0 8192
#define CR 32
#define CD 32
#define CS 512
#define CE 256
#define NV 256
#define OUT_T 5632
#define XSTRIDE 8192
#define NL 50
#define KCAT 1600   // 50 * 32

typedef __attribute__((ext_vector_type(8))) short  short8;
typedef __attribute__((ext_vector_type(4))) float  f32x4;
typedef __attribute__((ext_vector_type(4))) float  f4;
typedef __attribute__((ext_vector_type(4))) unsigned short us4;

static __device__ __forceinline__ unsigned short f2bf(float f) {
    unsigned int u = __builtin_bit_cast(unsigned int, f);
    u = (u + 0x7FFFu + ((u >> 16) & 1u)) >> 16;
    return (unsigned short)u;
}

// ---------------- Kernel P: weight f32 -> bf16 prep ----------------
__global__ __launch_bounds__(256) void k_prep(const float* __restrict__ sw,
                                              const float* __restrict__ w1,
                                              const float* __restrict__ w2,
                                              unsigned short* __restrict__ wsb,
                                              unsigned short* __restrict__ w1b,
                                              unsigned short* __restrict__ w2b)
{
    int idx = blockIdx.x * 256 + threadIdx.x;
    if (idx < NL * CS * CD) {
        int l = idx >> 14;
        int co = (idx >> 5) & 511;
        int c = idx & 31;
        wsb[co * KCAT + l * 32 + c] = f2bf(sw[idx]);
    } else if (idx < NL * CS * CD + CE * CS) {
        int e = idx - NL * CS * CD;
        w1b[e] = f2bf(w1[e]);
    } else {
        int e = idx - NL * CS * CD - CE * CS;
        w2b[e] = f2bf(w2[e]);
    }
}

// ---------------- Kernel A: embedding + causal pre-conv (k=2) ----------------
__global__ __launch_bounds__(256) void k_pre(const int* __restrict__ tokens,
                                             const float* __restrict__ emb,
                                             const float* __restrict__ pw,
                                             float* __restrict__ x)
{
    int idx = blockIdx.x * 256 + threadIdx.x;
    int t = idx & (L0 - 1);
    int o = (idx >> 13) & 31;
    int b = idx >> 18;
    const int* tb = tokens + b * L0;
    const float* e1 = emb + tb[t] * CR;
    const float* w = pw + o * CR * 2;
    float acc = 0.f;
    if (t > 0) {
        const float* e0 = emb + tb[t - 1] * CR;
#pragma unroll
        for (int i = 0; i < CR; ++i)
            acc += w[i * 2] * e0[i] + w[i * 2 + 1] * e1[i];
    } else {
#pragma unroll
        for (int i = 0; i < CR; ++i)
            acc += w[i * 2 + 1] * e1[i];
    }
    x[(b * CR + o) * XSTRIDE + t] = acc;
}

// ---------------- Kernel B: one WaveNet layer (round-3 config, VGPR-free) ----------------
__global__ __launch_bounds__(256) void k_layer(
    const float* __restrict__ x_in, float* __restrict__ x_out,
    unsigned short* __restrict__ Zt,
    const float* __restrict__ fw, const float* __restrict__ gw,
    const float* __restrict__ rw,
    int T_out, int d, int P, int skipOff, int kOff)
{
    __shared__ float As[32][68];
    __shared__ float Bs[32][68];
    __shared__ float Zs[32][68];
    __shared__ unsigned short ZsT[64][32];
    __shared__ float wfT[64][33];
    __shared__ float wgT[64][33];
    __shared__ float rwT[32][33];
    const int tid = threadIdx.x;
    const int t0 = blockIdx.x * 64;
    const int b = blockIdx.y;
    const float* xb = x_in + b * CR * XSTRIDE;

    for (int e = tid; e < 2048; e += 256) {
        int c = e >> 6, i2 = e & 63;
        wfT[i2][c] = fw[e];
        wgT[i2][c] = gw[e];
    }
    for (int e = tid; e < 1024; e += 256) {
        int c = e >> 5, i = e & 31;
        rwT[i][c] = rw[e];
    }
    {
        int ch = tid >> 3;
        int j0 = (tid & 7) * 8;
        const float* row = xb + ch * XSTRIDE;
#pragma unroll
        for (int k = 0; k < 8; ++k) {
            int t = t0 + j0 + k;
            float a = 0.f, bb = 0.f;
            if (t < T_out) {
                if (t >= P) a = row[t - P];
                bb = row[t + d - P];
            }
            As[ch][j0 + k] = a;
            Bs[ch][j0 + k] = bb;
        }
    }
    __syncthreads();
    {
        int c = tid & 31;
        int j0 = (tid >> 5) * 8;
        float af[8] = {0, 0, 0, 0, 0, 0, 0, 0};
        float ag[8] = {0, 0, 0, 0, 0, 0, 0, 0};
#pragma unroll
        for (int i = 0; i < 32; ++i) {
            float av[8], bv[8];
            *(f4*)&av[0] = *(const f4*)&As[i][j0];
            *(f4*)&av[4] = *(const f4*)&As[i][j0 + 4];
            *(f4*)&bv[0] = *(const f4*)&Bs[i][j0];
            *(f4*)&bv[4] = *(const f4*)&Bs[i][j0 + 4];
            float f0 = wfT[2 * i][c], f1 = wfT[2 * i + 1][c];
            float g0 = wgT[2 * i][c], g1 = wgT[2 * i + 1][c];
#pragma unroll
            for (int k = 0; k < 8; ++k) {
                af[k] += f0 * av[k] + f1 * bv[k];
                ag[k] += g0 * av[k] + g1 * bv[k];
            }
        }
#pragma unroll
        for (int k = 0; k < 8; ++k) {
            float e2a = __expf(2.f * af[k]);
            float th = 1.f - __fdividef(2.f, e2a + 1.f);
            float sg = __fdividef(1.f, 1.f + __expf(-ag[k]));
            float z = th * sg;
            Zs[c][j0 + k] = z;
            ZsT[j0 + k][c] = f2bf(z);
        }
    }
    __syncthreads();
    {
        int ch = tid >> 3;
        int j0 = (tid & 7) * 8;
        float accv[8];
        *(f4*)&accv[0] = *(const f4*)&Bs[ch][j0];
        *(f4*)&accv[4] = *(const f4*)&Bs[ch][j0 + 4];
#pragma unroll
        for (int i = 0; i < 32; ++i) {
            float w = rwT[i][ch];
            float zv[8];
            *(f4*)&zv[0] = *(const f4*)&Zs[i][j0];
            *(f4*)&zv[4] = *(const f4*)&Zs[i][j0 + 4];
#pragma unroll
            for (int k = 0; k < 8; ++k)
                accv[k] += w * zv[k];
        }
        float* orow = x_out + (b * CR + ch) * XSTRIDE;
#pragma unroll
        for (int k = 0; k < 8; ++k) {
            int t = t0 + j0 + k;
            if (t < T_out) orow[t] = accv[k];
        }
    }
    {
        int tl = tid >> 2;
        int cq = (tid & 3) * 8;
        int t = t0 + tl;
        if (t >= skipOff && t < T_out) {
            unsigned short* dst =
                Zt + ((size_t)b * OUT_T + (t - skipOff)) * KCAT + kOff + cq;
            *(short8*)dst = *(const short8*)&ZsT[tl][cq];
        }
    }
}

// ---------------- MFMA GEMM: C[b] = A * B[b]^T(+bias)(+relu), 128x128 tile ----------------
template <int MODE>
__global__ __launch_bounds__(256) void k_gemm(
    const unsigned short* __restrict__ A,
    const unsigned short* __restrict__ B,
    const float* __restrict__ bias,
    void* __restrict__ Cout, int M, int K)
{
    __shared__ unsigned short Asm[128][72];
    __shared__ unsigned short Bsm[128][72];
    const int tid = threadIdx.x;
    const int n0 = blockIdx.x * 128;
    const int m0 = blockIdx.y * 128;
    const int b = blockIdx.z;
    const unsigned short* Bb = B + (size_t)b * OUT_T * K;
    const int lane = tid & 63;
    const int wm = tid >> 6;
    f32x4 acc[2][8];
#pragma unroll
    for (int fm = 0; fm < 2; ++fm)
#pragma unroll
        for (int fn = 0; fn < 8; ++fn)
            acc[fm][fn] = (f32x4){0.f, 0.f, 0.f, 0.f};

    for (int kb = 0; kb < K; kb += 64) {
        __syncthreads();
#pragma unroll
        for (int it = 0; it < 4; ++it) {
            int lin = tid + it * 256;
            int row = lin >> 3, c8 = (lin & 7) * 8;
            *(short8*)&Asm[row][c8] =
                *(const short8*)&A[(size_t)(m0 + row) * K + kb + c8];
        }
#pragma unroll
        for (int it = 0; it < 4; ++it) {
            int lin = tid + it * 256;
            int row = lin >> 3, c8 = (lin & 7) * 8;
            *(short8*)&Bsm[row][c8] =
                *(const short8*)&Bb[(size_t)(n0 + row) * K + kb + c8];
        }
        __syncthreads();
#pragma unroll
        for (int kk = 0; kk < 2; ++kk) {
            short8 a[2], bb[8];
#pragma unroll
            for (int fm = 0; fm < 2; ++fm)
                a[fm] = *(const short8*)&Asm[wm * 32 + fm * 16 + (lane & 15)]
                                           [kk * 32 + (lane >> 4) * 8];
#pragma unroll
            for (int fn = 0; fn < 8; ++fn)
                bb[fn] = *(const short8*)&Bsm[fn * 16 + (lane & 15)]
                                            [kk * 32 + (lane >> 4) * 8];
#pragma unroll
            for (int fm = 0; fm < 2; ++fm)
#pragma unroll
                for (int fn = 0; fn < 8; ++fn)
                    acc[fm][fn] = __builtin_amdgcn_mfma_f32_16x16x32_bf16(
                        a[fm], bb[fn], acc[fm][fn], 0, 0, 0);
        }
    }
#pragma unroll
    for (int fm = 0; fm < 2; ++fm) {
        int mb = m0 + wm * 32 + fm * 16 + (lane >> 4) * 4;
#pragma unroll
        for (int fn = 0; fn < 8; ++fn) {
            int n = n0 + fn * 16 + (lane & 15);
            float v[4];
#pragma unroll
            for (int r = 0; r < 4; ++r) {
                v[r] = acc[fm][fn][r];
                if (MODE >= 1) v[r] += bias[mb + r];
                if (MODE <= 1) v[r] = v[r] > 0.f ? v[r] : 0.f;
            }
            if (MODE == 2) {
                float* o = (float*)Cout;
#pragma unroll
                for (int r = 0; r < 4; ++r)
                    o[((size_t)b * NV + mb + r) * OUT_T + n] = v[r];
            } else {
                unsigned short* o = (unsigned short*)Cout;
                us4 pk;
#pragma unroll
                for (int r = 0; r < 4; ++r) pk[r] = f2bf(v[r]);
                *(us4*)&o[((size_t)b * OUT_T + n) * M + mb] = pk;
            }
        }
    }
}

extern "C" void kernel_launch(void* const* d_in, const int* in_sizes, int n_in,
                              void* d_out, int out_size, void* d_ws, size_t ws_size,
                              hipStream_t stream)
{
    const int*   tokens  = (const int*)d_in[0];
    const float* emb     = (const float*)d_in[1];
    const float* pre_w   = (const float*)d_in[2];
    const float* filt_w  = (const float*)d_in[3];
    const float* gate_w  = (const float*)d_in[4];
    const float* res_w   = (const float*)d_in[5];
    const float* skip_w  = (const float*)d_in[6];
    const float* post_w1 = (const float*)d_in[7];
    const float* post_b1 = (const float*)d_in[8];
    const float* post_w2 = (const float*)d_in[9];
    const float* post_b2 = (const float*)d_in[10];
    float* out = (float*)d_out;

    char* ws = (char*)d_ws;
    float* xA = (float*)ws;                 ws += (size_t)NB * CR * XSTRIDE * 4;
    float* xB = (float*)ws;                 ws += (size_t)NB * CR * XSTRIDE * 4;
    unsigned short* Zt    = (unsigned short*)ws; ws += (size_t)NB * OUT_T * KCAT * 2;
    unsigned short* skipT = (unsigned short*)ws; ws += (size_t)NB * OUT_T * CS * 2;
    unsigned short* h1T   = (unsigned short*)ws; ws += (size_t)NB * OUT_T * CE * 2;
    unsigned short* wsb   = (unsigned short*)ws; ws += (size_t)CS * KCAT * 2;
    unsigned short* w1b   = (unsigned short*)ws; ws += (size_t)CE * CS * 2;
    unsigned short* w2b   = (unsigned short*)ws; ws += (size_t)NV * CE * 2;

    k_prep<<<3968, 256, 0, stream>>>(skip_w, post_w1, post_w2, wsb, w1b, w2b);
    k_pre<<<(NB * CR * L0) / 256, 256, 0, stream>>>(tokens, emb, pre_w, xA);

    // static layer schedule (mirrors reference dilate() padding)
    int dArr[NL], pArr[NL], tArr[NL];
    {
        int T = L0, init = 1, li = 0;
        for (int blk = 0; blk < 5; ++blk) {
            int nw = 1;
            for (int j = 0; j < 10; ++j) {
                int d = nw, P = 0;
                if (d > init) {
                    int r = d / init;
                    int l = T / init;
                    int nl = ((l + r - 1) / r) * r;
                    P = (nl - l) * init;
                }
                int T_out = T + P - d;
                dArr[li] = d; pArr[li] = P; tArr[li] = T_out;
                T = T_out; init = d; nw <<= 1; ++li;
            }
        }
    }

    float* xin = xA;
    float* xout = xB;
    for (int li = 0; li < NL; ++li) {
        int T_out = tArr[li];
        dim3 grid((T_out + 63) / 64, NB);
        k_layer<<<grid, 256, 0, stream>>>(
            xin, xout, Zt,
            filt_w + (size_t)li * CD * CR * 2,
            gate_w + (size_t)li * CD * CR * 2,
            res_w + (size_t)li * CR * CD,
            T_out, dArr[li], pArr[li], T_out - OUT_T, li * 32);
        float* tmp = xin; xin = xout; xout = tmp;
    }

    dim3 gs(OUT_T / 128, CS / 128, NB);
    k_gemm<0><<<gs, 256, 0, stream>>>(wsb, Zt, nullptr, skipT, CS, KCAT);
    dim3 g1(OUT_T / 128, CE / 128, NB);
    k_gemm<1><<<g1, 256, 0, stream>>>(w1b, skipT, post_b1, h1T, CE, CS);
    dim3 g2(OUT_T / 128, NV / 128, NB);
    k_gemm<2><<<g2, 256, 0, stream>>>(w2b, h1T, post_b2, out, NV, CE);
}